// Round 16
// baseline (361.761 us; speedup 1.0000x reference)
//
#include <hip/hip_runtime.h>

// ---------------------------------------------------------------------------
// GCN 2-layer forward on MI355X.
// out = relu(Ahat * relu((Ahat*X)*W1 + b1) * W2 + b2),  Ahat = D^-1/2 (A+I) D^-1/2
// R3: GEMMs = bf16-split MFMA (Ootomo 3-mult). R9: record-based agg (batch-8).
// R11: XCD-partitioned CSR fill (plain R13 form: nt/4-wide variants all ~equal
//     or worse -> scattered-atomic writeback floor ~45us, frozen).
// R12/13: GEMM 32x128 LDS tile -> 301.7us.
// R16: GEMM -> direct-streaming, NO LDS, NO barriers: K-loop was only 4/8
//     iters so barrier drains+prologue dominated; waves load packed A/B frags
//     from global (A shared by 4 waves -> L1; B 128KB L2-resident), unpack
//     in-register (same VALU as staging did), 12 MFMA/kstep.
// ---------------------------------------------------------------------------

#define C_IN   128
#define C_HID  256
#define C_OUT  128

typedef __attribute__((ext_vector_type(8))) short short8;
typedef __attribute__((ext_vector_type(4))) float floatx4;

__device__ __forceinline__ unsigned short f2bf(float f) {
    unsigned u = __float_as_uint(f);
    u += 0x7FFFu + ((u >> 16) & 1u);      // RNE
    return (unsigned short)(u >> 16);
}
__device__ __forceinline__ float bf2f(unsigned short b) {
    return __uint_as_float(((unsigned)b) << 16);
}
__device__ __forceinline__ unsigned pack_hilo(float f) {
    unsigned short hi = f2bf(f);
    unsigned short lo = f2bf(f - bf2f(hi));
    return ((unsigned)hi << 16) | (unsigned)lo;
}
__device__ __forceinline__ float bflo(unsigned v) {
    return __uint_as_float((v & 0xFFFFu) << 16);
}
__device__ __forceinline__ float bfhi(unsigned v) {
    return __uint_as_float(v & 0xFFFF0000u);
}
__device__ __forceinline__ void unpack8(uint4 x, uint4 y, short8& hi, short8& lo) {
    unsigned u[8] = {x.x, x.y, x.z, x.w, y.x, y.y, y.z, y.w};
    #pragma unroll
    for (int j = 0; j < 8; ++j) {
        hi[j] = (short)(u[j] >> 16);
        lo[j] = (short)(u[j] & 0xFFFFu);
    }
}

// ---------------- degree histogram ----------------
__global__ void deg_kernel(const int* __restrict__ dst, int* __restrict__ counts, int E) {
    int e = blockIdx.x * blockDim.x + threadIdx.x;
    if (e < E) atomicAdd(&counts[dst[e]], 1);
}

// ---------------- multi-block scan: 1024 counts per block ----------------
#define SCHUNK 1024

__global__ __launch_bounds__(256) void scan_reduce(const int* __restrict__ counts,
                                                   int* __restrict__ block_sums, int n) {
    int b = blockIdx.x;
    int base = b * SCHUNK;
    int t = threadIdx.x;
    int s = 0;
    #pragma unroll
    for (int u = 0; u < 4; ++u) {
        int i = base + t * 4 + u;
        if (i < n) s += counts[i];
    }
    #pragma unroll
    for (int off = 32; off; off >>= 1) s += __shfl_down(s, off, 64);
    __shared__ int ws[4];
    int wave = t >> 6;
    if ((t & 63) == 0) ws[wave] = s;
    __syncthreads();
    if (t == 0) block_sums[b] = ws[0] + ws[1] + ws[2] + ws[3];
}

__global__ __launch_bounds__(64) void scan_sums(const int* __restrict__ block_sums,
                                                int* __restrict__ block_base, int nb,
                                                int* __restrict__ offsets, int n, int E) {
    int t = threadIdx.x;
    int v = (t < nb) ? block_sums[t] : 0;
    int x = v;
    #pragma unroll
    for (int off = 1; off < 64; off <<= 1) {
        int y = __shfl_up(x, off, 64);
        if (t >= off) x += y;
    }
    if (t < nb) block_base[t] = x - v;
    if (t == 0) offsets[n] = E;
}

// reads counts (PRESERVED), writes offsets + cursor (separate) + fused dinv.
__global__ __launch_bounds__(256) void scan_apply(const int* __restrict__ counts,
                                                  const int* __restrict__ block_base,
                                                  int* __restrict__ offsets,
                                                  int* __restrict__ cursor,
                                                  float* __restrict__ dinv, int n) {
    int b = blockIdx.x;
    int base_i = b * SCHUNK;
    int t = threadIdx.x;
    int c[4];
    #pragma unroll
    for (int u = 0; u < 4; ++u) {
        int i = base_i + t * 4 + u;
        c[u] = (i < n) ? counts[i] : 0;
    }
    int tot = c[0] + c[1] + c[2] + c[3];
    int x = tot;
    int lane = t & 63;
    #pragma unroll
    for (int off = 1; off < 64; off <<= 1) {
        int y = __shfl_up(x, off, 64);
        if (lane >= off) x += y;
    }
    __shared__ int ws[4];
    int wave = t >> 6;
    if (lane == 63) ws[wave] = x;
    __syncthreads();
    int wbase = 0;
    for (int w = 0; w < wave; ++w) wbase += ws[w];
    int run = block_base[b] + wbase + (x - tot);
    #pragma unroll
    for (int u = 0; u < 4; ++u) {
        int i = base_i + t * 4 + u;
        if (i < n) {
            offsets[i] = run;
            cursor[i]  = run;
            dinv[i]    = rsqrtf((float)(c[u] + 1));   // +1 self-loop
            run += c[u];
        }
    }
}

// ---------------- XCD-partitioned CSR fill (R13 plain — frozen) -------------
__global__ __launch_bounds__(256) void fill_csr_part(
        const int* __restrict__ src, const int* __restrict__ dst,
        const int* __restrict__ counts, int* __restrict__ cursor,
        unsigned* __restrict__ csr_pk, int E, int n) {
    int group = blockIdx.x & 7;
    int sub   = blockIdx.x >> 3;
    int nblk  = gridDim.x >> 3;            // blocks per group
    int chunk = (n + 7) / 8;
    int nlo = group * chunk;
    int nhi = min(n, nlo + chunk);
    int stride = nblk * 256;
    for (int e = sub * 256 + threadIdx.x; e < E; e += stride) {
        int d = dst[e];
        if (d >= nlo && d < nhi) {
            int s = src[e];
            unsigned rec = (unsigned)s | ((unsigned)counts[s] << 17);
            int p = atomicAdd(&cursor[d], 1);
            csr_pk[p] = rec;
        }
    }
}

// ---------------- weight cast+transpose: W[K][N] f32 -> Wt[N][K] packed ----
__global__ void cast_w_t(const float* __restrict__ W, unsigned* __restrict__ Wtp,
                         int K, int N) {
    int idx = blockIdx.x * blockDim.x + threadIdx.x;
    if (idx < K * N) {
        int k = idx / N, nn = idx - k * N;
        Wtp[(size_t)nn * K + k] = pack_hilo(W[idx]);
    }
}

// ---------------- x -> bf16 cast, 4 elems/thread ----------------
__global__ void cast_x_bf16(const float* __restrict__ x, unsigned* __restrict__ xb2,
                            int count4) {
    int idx = blockIdx.x * blockDim.x + threadIdx.x;
    if (idx < count4) {
        float4 f = ((const float4*)x)[idx];
        unsigned lo = (unsigned)f2bf(f.x) | ((unsigned)f2bf(f.y) << 16);
        unsigned hi = (unsigned)f2bf(f.z) | ((unsigned)f2bf(f.w) << 16);
        ((uint2*)xb2)[idx] = make_uint2(lo, hi);
    }
}

// ---------------- pull aggregation: wave/node, batch-8 (R13 exact) ----------
__global__ __launch_bounds__(256) void agg_kernel(
        const unsigned short* __restrict__ hb, const int* __restrict__ offsets,
        const unsigned* __restrict__ csr_pk, const float* __restrict__ dinv,
        const float* __restrict__ bias, float* __restrict__ out_f,
        unsigned* __restrict__ out_p, int relu_flag, int n) {
    int node = blockIdx.x * 4 + (threadIdx.x >> 6);
    if (node >= n) return;
    int lane = threadIdx.x & 63;

    const unsigned* hrow = (const unsigned*)hb;   // row j = 64 uints
    float di = dinv[node];
    unsigned sv = hrow[(size_t)node * 64 + lane];
    float a0 = di * bflo(sv);
    float a1 = di * bfhi(sv);

    int lo = offsets[node], hi = offsets[node + 1];

    unsigned rec[8];
    #pragma unroll
    for (int u = 0; u < 8; ++u)
        rec[u] = __builtin_nontemporal_load(&csr_pk[lo + u]);   // slack covers deg==0

    for (int k = lo; k < hi; k += 8) {
        int jj[8]; float w[8];
        #pragma unroll
        for (int u = 0; u < 8; ++u) {
            bool ok = (k + u) < hi;
            jj[u] = ok ? (int)(rec[u] & 0x1FFFFu) : 0;
            w[u]  = ok ? rsqrtf((float)((rec[u] >> 17) + 1u)) : 0.0f;
        }
        unsigned v[8];
        #pragma unroll
        for (int u = 0; u < 8; ++u)
            v[u] = hrow[(size_t)jj[u] * 64 + lane];
        #pragma unroll
        for (int u = 0; u < 8; ++u)                             // prefetch next batch
            rec[u] = __builtin_nontemporal_load(&csr_pk[k + 8 + u]);
        #pragma unroll
        for (int u = 0; u < 8; ++u) {
            a0 += w[u] * bflo(v[u]);
            a1 += w[u] * bfhi(v[u]);
        }
    }

    int c0 = lane * 2;
    float v0 = di * a0, v1f = di * a1;
    if (bias) { v0 += bias[c0]; v1f += bias[c0 + 1]; }
    if (relu_flag) { v0 = fmaxf(v0, 0.0f); v1f = fmaxf(v1f, 0.0f); }
    if (out_f) {
        unsigned long long ov = ((unsigned long long)__float_as_uint(v1f) << 32)
                              | (unsigned long long)__float_as_uint(v0);
        __builtin_nontemporal_store(ov, (unsigned long long*)(out_f + (size_t)node * 128 + c0));
    } else {
        unsigned long long ov = ((unsigned long long)pack_hilo(v1f) << 32)
                              | (unsigned long long)pack_hilo(v0);
        __builtin_nontemporal_store(ov, (unsigned long long*)(out_p + (size_t)node * 128 + c0));
    }
}

// ---------------- direct-streaming bf16-split MFMA GEMM (R16) ---------------
// C = A*B (+bias)(relu). A: [M][K] packed hi|lo uints. Btp: [N][K] packed.
// NO LDS, NO barriers. Block = 4 waves; wave covers rows row0..row0+31 x
// cols col0+wv*32..+31 as 2x2 frags of 16x16x32 (3 mults each).
// Frag loads straight from global: A lines shared by all 4 waves (L1),
// B rows L2-resident (Wt = 128KB). Unpack hi/lo in-register.
__global__ __launch_bounds__(256) void mfma_gemm(
        const unsigned* __restrict__ Ap, const unsigned* __restrict__ Btp,
        const float* __restrict__ bias, float* __restrict__ Cf,
        unsigned* __restrict__ Cp, unsigned short* __restrict__ Cb,
        int M, int K, int N, int relu_flag) {
    int tid = threadIdx.x;
    int lane = tid & 63;
    int wv = tid >> 6;
    int row0 = blockIdx.x * 32;
    int col0 = blockIdx.y * 128 + wv * 32;
    int l15 = lane & 15;
    int ko  = (lane >> 4) * 8;        // uint offset within a 32-k step

    int ar0 = min(row0 + l15, M - 1);        // clamp: rows >= M never stored
    int ar1 = min(row0 + 16 + l15, M - 1);
    const unsigned* pa0 = Ap + (size_t)ar0 * K + ko;
    const unsigned* pa1 = Ap + (size_t)ar1 * K + ko;
    const unsigned* pb0 = Btp + (size_t)(col0 + l15) * K + ko;
    const unsigned* pb1 = Btp + (size_t)(col0 + 16 + l15) * K + ko;

    floatx4 acc[2][2];
    #pragma unroll
    for (int i = 0; i < 2; ++i)
        #pragma unroll
        for (int j = 0; j < 2; ++j)
            acc[i][j] = (floatx4){0.f, 0.f, 0.f, 0.f};

    for (int k0 = 0; k0 < K; k0 += 32) {
        uint4 a0x = *(const uint4*)(pa0 + k0);
        uint4 a0y = *(const uint4*)(pa0 + k0 + 4);
        uint4 a1x = *(const uint4*)(pa1 + k0);
        uint4 a1y = *(const uint4*)(pa1 + k0 + 4);
        uint4 b0x = *(const uint4*)(pb0 + k0);
        uint4 b0y = *(const uint4*)(pb0 + k0 + 4);
        uint4 b1x = *(const uint4*)(pb1 + k0);
        uint4 b1y = *(const uint4*)(pb1 + k0 + 4);

        short8 ah[2], al[2], bh[2], bl[2];
        unpack8(a0x, a0y, ah[0], al[0]);
        unpack8(a1x, a1y, ah[1], al[1]);
        unpack8(b0x, b0y, bh[0], bl[0]);
        unpack8(b1x, b1y, bh[1], bl[1]);

        #pragma unroll
        for (int mi = 0; mi < 2; ++mi)
            #pragma unroll
            for (int ni = 0; ni < 2; ++ni) {
                acc[mi][ni] = __builtin_amdgcn_mfma_f32_16x16x32_bf16(al[mi], bh[ni], acc[mi][ni], 0, 0, 0);
                acc[mi][ni] = __builtin_amdgcn_mfma_f32_16x16x32_bf16(ah[mi], bl[ni], acc[mi][ni], 0, 0, 0);
                acc[mi][ni] = __builtin_amdgcn_mfma_f32_16x16x32_bf16(ah[mi], bh[ni], acc[mi][ni], 0, 0, 0);
            }
    }

    // epilogue: C/D mapping col=lane&15, row=(lane>>4)*4+reg
    #pragma unroll
    for (int mi = 0; mi < 2; ++mi) {
        #pragma unroll
        for (int reg = 0; reg < 4; ++reg) {
            int r = row0 + mi * 16 + (lane >> 4) * 4 + reg;
            if (r < M) {
                #pragma unroll
                for (int ni = 0; ni < 2; ++ni) {
                    int c = col0 + ni * 16 + l15;
                    float v = acc[mi][ni][reg];
                    if (bias) v += bias[c];
                    if (relu_flag) v = fmaxf(v, 0.0f);
                    if (Cf)      Cf[(size_t)r * N + c] = v;
                    else if (Cp) Cp[(size_t)r * N + c] = pack_hilo(v);
                    else         Cb[(size_t)r * N + c] = f2bf(v);
                }
            }
        }
    }
}

// ---------------------------------------------------------------------------
extern "C" void kernel_launch(void* const* d_in, const int* in_sizes, int n_in,
                              void* d_out, int out_size, void* d_ws, size_t ws_size,
                              hipStream_t stream) {
    const float* x  = (const float*)d_in[0];
    const int*   ei = (const int*)d_in[1];
    const float* W1 = (const float*)d_in[2];
    const float* b1 = (const float*)d_in[3];
    const float* W2 = (const float*)d_in[4];
    const float* b2 = (const float*)d_in[5];

    const int n = in_sizes[0] / C_IN;          // 50000
    const int E = in_sizes[1] / 2;             // 800000

    const int* src = ei;
    const int* dst = ei + E;

    // workspace layout (~81 MB)
    unsigned short* h2b = (unsigned short*)d_ws;         // n*128 bf16
    unsigned* z1p = (unsigned*)(h2b + (size_t)n * C_OUT);// n*256 packed
    unsigned short* xb = (unsigned short*)(z1p + (size_t)n * C_HID); // n*128 bf16
    unsigned* w1t = (unsigned*)(xb + (size_t)n * C_IN);  // 128*256
    unsigned* w2t = w1t + C_IN * C_HID;                  // 256*128
    float*    dinv = (float*)(w2t + C_HID * C_OUT);      // n
    int* counts  = (int*)(dinv + n);                     // n (preserved)
    int* cursor  = counts + n;                           // n (separate)
    int* offsets = cursor + n;                           // n+1
    unsigned* csr_pk = (unsigned*)(offsets + n + 1);     // E uint (+64 slack)
    int* block_sums = (int*)(csr_pk + E + 64);           // 64
    int* block_base = block_sums + 64;                   // 64

    unsigned* agg0p = (unsigned*)d_out;    // n*128 packed, overwritten by final out
    float*    outp  = (float*)d_out;

    const int nb = (n + SCHUNK - 1) / SCHUNK;            // 49

    // ---- CSR build ----
    hipMemsetAsync(counts, 0, (size_t)n * sizeof(int), stream);
    deg_kernel<<<(E + 255) / 256, 256, 0, stream>>>(dst, counts, E);
    scan_reduce<<<nb, 256, 0, stream>>>(counts, block_sums, n);
    scan_sums<<<1, 64, 0, stream>>>(block_sums, block_base, nb, offsets, n, E);
    scan_apply<<<nb, 256, 0, stream>>>(counts, block_base, offsets, cursor, dinv, n);
    fill_csr_part<<<8 * 391, 256, 0, stream>>>(src, dst, counts, cursor, csr_pk, E, n);

    // ---- casts (tiny) ----
    cast_w_t<<<(C_IN * C_HID + 255) / 256, 256, 0, stream>>>(W1, w1t, C_IN, C_HID);
    cast_w_t<<<(C_HID * C_OUT + 255) / 256, 256, 0, stream>>>(W2, w2t, C_HID, C_OUT);
    {
        int count4 = n * C_IN / 4;
        cast_x_bf16<<<(count4 + 255) / 256, 256, 0, stream>>>(x, (unsigned*)xb, count4);
    }

    const int agg_blocks = (n + 3) / 4;

    // ---- layer 1: agg0 = Ahat*X (packed) ; z1 = relu(agg0@W1 + b1) (packed) ----
    agg_kernel<<<agg_blocks, 256, 0, stream>>>(xb, offsets, csr_pk,
                                               dinv, nullptr, nullptr, agg0p, 0, n);
    {
        dim3 grid((n + 31) / 32, C_HID / 128);           // (1563, 2)
        mfma_gemm<<<grid, 256, 0, stream>>>(agg0p, w1t, b1, nullptr, z1p, nullptr,
                                            n, C_IN, C_HID, 1);
    }

    // ---- layer 2: h2 = z1@W2 (bf16) ; out = relu(Ahat*h2 + b2) ----
    {
        dim3 grid((n + 31) / 32, C_OUT / 128);           // (1563, 1)
        mfma_gemm<<<grid, 256, 0, stream>>>(z1p, w2t, nullptr, nullptr, nullptr, h2b,
                                            n, C_HID, C_OUT, 0);
    }
    agg_kernel<<<agg_blocks, 256, 0, stream>>>(h2b, offsets, csr_pk,
                                               dinv, b2, outp, nullptr, 1, n);
}

// Round 17
// 298.361 us; speedup vs baseline: 1.2125x; 1.2125x over previous
//
#include <hip/hip_runtime.h>

// ---------------------------------------------------------------------------
// GCN 2-layer forward on MI355X.
// out = relu(Ahat * relu((Ahat*X)*W1 + b1) * W2 + b2),  Ahat = D^-1/2 (A+I) D^-1/2
// R3: GEMMs = bf16-split MFMA (Ootomo 3-mult). R9: record-based agg (batch-8).
// R11: XCD-partitioned CSR fill (frozen at ~45us scatter-fabric floor).
// R12/13: GEMM 32x128 LDS tile -> 301.7us best.
// R16 REVERTED: no-LDS streaming GEMM regressed 38->64us/ea — fragment loads
//     are uncoalesced (16 lines/inst); LDS staging is the coalescing device.
// R17: R13 exact + fuse deg+cast_x+cast_w into ONE launch (independent work;
//     deg is atomic-latency-bound at 5% pipe use, casts stream behind it).
// ---------------------------------------------------------------------------

#define C_IN   128
#define C_HID  256
#define C_OUT  128

typedef __attribute__((ext_vector_type(8))) short short8;
typedef __attribute__((ext_vector_type(4))) short bfs4;
typedef __attribute__((ext_vector_type(4))) float floatx4;

__device__ __forceinline__ unsigned short f2bf(float f) {
    unsigned u = __float_as_uint(f);
    u += 0x7FFFu + ((u >> 16) & 1u);      // RNE
    return (unsigned short)(u >> 16);
}
__device__ __forceinline__ float bf2f(unsigned short b) {
    return __uint_as_float(((unsigned)b) << 16);
}
__device__ __forceinline__ unsigned pack_hilo(float f) {
    unsigned short hi = f2bf(f);
    unsigned short lo = f2bf(f - bf2f(hi));
    return ((unsigned)hi << 16) | (unsigned)lo;
}
__device__ __forceinline__ float bflo(unsigned v) {
    return __uint_as_float((v & 0xFFFFu) << 16);
}
__device__ __forceinline__ float bfhi(unsigned v) {
    return __uint_as_float(v & 0xFFFF0000u);
}

// ---------------- fused pre-pass: deg histogram + all casts (R17) -----------
// Independent work partitioned by blockIdx range; deg blocks FIRST so the
// latency-bound atomics start immediately, cast streaming hides behind them.
__global__ __launch_bounds__(256) void fused_pre(
        const int* __restrict__ dst, int* __restrict__ counts, int E,
        const float* __restrict__ x, unsigned* __restrict__ xb2, int count4,
        const float* __restrict__ W1, unsigned* __restrict__ w1t,
        const float* __restrict__ W2, unsigned* __restrict__ w2t,
        int nb_deg, int nb_x, int nb_w1) {
    int b = blockIdx.x;
    int t = threadIdx.x;
    if (b < nb_deg) {
        int e = b * 256 + t;
        if (e < E) atomicAdd(&counts[dst[e]], 1);
    } else if (b < nb_deg + nb_x) {
        int idx = (b - nb_deg) * 256 + t;
        if (idx < count4) {
            float4 f = ((const float4*)x)[idx];
            unsigned lo = (unsigned)f2bf(f.x) | ((unsigned)f2bf(f.y) << 16);
            unsigned hi = (unsigned)f2bf(f.z) | ((unsigned)f2bf(f.w) << 16);
            ((uint2*)xb2)[idx] = make_uint2(lo, hi);
        }
    } else if (b < nb_deg + nb_x + nb_w1) {
        int idx = (b - nb_deg - nb_x) * 256 + t;
        if (idx < C_IN * C_HID) {
            int k = idx / C_HID, nn = idx - k * C_HID;
            w1t[(size_t)nn * C_IN + k] = pack_hilo(W1[idx]);
        }
    } else {
        int idx = (b - nb_deg - nb_x - nb_w1) * 256 + t;
        if (idx < C_HID * C_OUT) {
            int k = idx / C_OUT, nn = idx - k * C_OUT;
            w2t[(size_t)nn * C_HID + k] = pack_hilo(W2[idx]);
        }
    }
}

// ---------------- multi-block scan: 1024 counts per block ----------------
#define SCHUNK 1024

__global__ __launch_bounds__(256) void scan_reduce(const int* __restrict__ counts,
                                                   int* __restrict__ block_sums, int n) {
    int b = blockIdx.x;
    int base = b * SCHUNK;
    int t = threadIdx.x;
    int s = 0;
    #pragma unroll
    for (int u = 0; u < 4; ++u) {
        int i = base + t * 4 + u;
        if (i < n) s += counts[i];
    }
    #pragma unroll
    for (int off = 32; off; off >>= 1) s += __shfl_down(s, off, 64);
    __shared__ int ws[4];
    int wave = t >> 6;
    if ((t & 63) == 0) ws[wave] = s;
    __syncthreads();
    if (t == 0) block_sums[b] = ws[0] + ws[1] + ws[2] + ws[3];
}

__global__ __launch_bounds__(64) void scan_sums(const int* __restrict__ block_sums,
                                                int* __restrict__ block_base, int nb,
                                                int* __restrict__ offsets, int n, int E) {
    int t = threadIdx.x;
    int v = (t < nb) ? block_sums[t] : 0;
    int x = v;
    #pragma unroll
    for (int off = 1; off < 64; off <<= 1) {
        int y = __shfl_up(x, off, 64);
        if (t >= off) x += y;
    }
    if (t < nb) block_base[t] = x - v;
    if (t == 0) offsets[n] = E;
}

// reads counts (PRESERVED), writes offsets + cursor (separate) + fused dinv.
__global__ __launch_bounds__(256) void scan_apply(const int* __restrict__ counts,
                                                  const int* __restrict__ block_base,
                                                  int* __restrict__ offsets,
                                                  int* __restrict__ cursor,
                                                  float* __restrict__ dinv, int n) {
    int b = blockIdx.x;
    int base_i = b * SCHUNK;
    int t = threadIdx.x;
    int c[4];
    #pragma unroll
    for (int u = 0; u < 4; ++u) {
        int i = base_i + t * 4 + u;
        c[u] = (i < n) ? counts[i] : 0;
    }
    int tot = c[0] + c[1] + c[2] + c[3];
    int x = tot;
    int lane = t & 63;
    #pragma unroll
    for (int off = 1; off < 64; off <<= 1) {
        int y = __shfl_up(x, off, 64);
        if (lane >= off) x += y;
    }
    __shared__ int ws[4];
    int wave = t >> 6;
    if (lane == 63) ws[wave] = x;
    __syncthreads();
    int wbase = 0;
    for (int w = 0; w < wave; ++w) wbase += ws[w];
    int run = block_base[b] + wbase + (x - tot);
    #pragma unroll
    for (int u = 0; u < 4; ++u) {
        int i = base_i + t * 4 + u;
        if (i < n) {
            offsets[i] = run;
            cursor[i]  = run;
            dinv[i]    = rsqrtf((float)(c[u] + 1));   // +1 self-loop
            run += c[u];
        }
    }
}

// ---------------- XCD-partitioned CSR fill (R13 plain — frozen) -------------
__global__ __launch_bounds__(256) void fill_csr_part(
        const int* __restrict__ src, const int* __restrict__ dst,
        const int* __restrict__ counts, int* __restrict__ cursor,
        unsigned* __restrict__ csr_pk, int E, int n) {
    int group = blockIdx.x & 7;
    int sub   = blockIdx.x >> 3;
    int nblk  = gridDim.x >> 3;            // blocks per group
    int chunk = (n + 7) / 8;
    int nlo = group * chunk;
    int nhi = min(n, nlo + chunk);
    int stride = nblk * 256;
    for (int e = sub * 256 + threadIdx.x; e < E; e += stride) {
        int d = dst[e];
        if (d >= nlo && d < nhi) {
            int s = src[e];
            unsigned rec = (unsigned)s | ((unsigned)counts[s] << 17);
            int p = atomicAdd(&cursor[d], 1);
            csr_pk[p] = rec;
        }
    }
}

// ---------------- pull aggregation: wave/node, batch-8 (R13 exact) ----------
__global__ __launch_bounds__(256) void agg_kernel(
        const unsigned short* __restrict__ hb, const int* __restrict__ offsets,
        const unsigned* __restrict__ csr_pk, const float* __restrict__ dinv,
        const float* __restrict__ bias, float* __restrict__ out_f,
        unsigned* __restrict__ out_p, int relu_flag, int n) {
    int node = blockIdx.x * 4 + (threadIdx.x >> 6);
    if (node >= n) return;
    int lane = threadIdx.x & 63;

    const unsigned* hrow = (const unsigned*)hb;   // row j = 64 uints
    float di = dinv[node];
    unsigned sv = hrow[(size_t)node * 64 + lane];
    float a0 = di * bflo(sv);
    float a1 = di * bfhi(sv);

    int lo = offsets[node], hi = offsets[node + 1];

    unsigned rec[8];
    #pragma unroll
    for (int u = 0; u < 8; ++u)
        rec[u] = __builtin_nontemporal_load(&csr_pk[lo + u]);   // slack covers deg==0

    for (int k = lo; k < hi; k += 8) {
        int jj[8]; float w[8];
        #pragma unroll
        for (int u = 0; u < 8; ++u) {
            bool ok = (k + u) < hi;
            jj[u] = ok ? (int)(rec[u] & 0x1FFFFu) : 0;
            w[u]  = ok ? rsqrtf((float)((rec[u] >> 17) + 1u)) : 0.0f;
        }
        unsigned v[8];
        #pragma unroll
        for (int u = 0; u < 8; ++u)
            v[u] = hrow[(size_t)jj[u] * 64 + lane];
        #pragma unroll
        for (int u = 0; u < 8; ++u)                             // prefetch next batch
            rec[u] = __builtin_nontemporal_load(&csr_pk[k + 8 + u]);
        #pragma unroll
        for (int u = 0; u < 8; ++u) {
            a0 += w[u] * bflo(v[u]);
            a1 += w[u] * bfhi(v[u]);
        }
    }

    int c0 = lane * 2;
    float v0 = di * a0, v1f = di * a1;
    if (bias) { v0 += bias[c0]; v1f += bias[c0 + 1]; }
    if (relu_flag) { v0 = fmaxf(v0, 0.0f); v1f = fmaxf(v1f, 0.0f); }
    if (out_f) {
        unsigned long long ov = ((unsigned long long)__float_as_uint(v1f) << 32)
                              | (unsigned long long)__float_as_uint(v0);
        __builtin_nontemporal_store(ov, (unsigned long long*)(out_f + (size_t)node * 128 + c0));
    } else {
        unsigned long long ov = ((unsigned long long)pack_hilo(v1f) << 32)
                              | (unsigned long long)pack_hilo(v0);
        __builtin_nontemporal_store(ov, (unsigned long long*)(out_p + (size_t)node * 128 + c0));
    }
}

// ---------------- bf16-split MFMA GEMM, 32x128 tile (R13 exact) -------------
#define TM 32
#define TN 128
#define TK 32
#define LDK 40    // halfs per LDS row: 80B stride -> b128 frag reads 2-way (free)

__global__ __launch_bounds__(256) void mfma_gemm(
        const unsigned* __restrict__ Ap, const unsigned* __restrict__ Btp,
        const float* __restrict__ bias, float* __restrict__ Cf,
        unsigned* __restrict__ Cp, unsigned short* __restrict__ Cb,
        int M, int K, int N, int relu_flag) {
    __shared__ unsigned short smem[320 * LDK];       // 25.6 KB
    unsigned short* As_hi = smem;                    // 32 rows
    unsigned short* As_lo = smem + 32 * LDK;         // 32 rows
    unsigned short* Bs_hi = smem + 64 * LDK;         // 128 rows
    unsigned short* Bs_lo = smem + 192 * LDK;        // 128 rows

    int tid = threadIdx.x;
    int lane = tid & 63;
    int wv = tid >> 6;
    int n0w = wv * 32;
    int row0 = blockIdx.x * TM;
    int col0 = blockIdx.y * TN;

    int a_r  = tid >> 3;           // 0..31
    int a_kc = (tid & 7) * 4;      // 0,4,..,28
    int b_r  = tid >> 2;           // 0..63
    int b_kc = (tid & 3) * 8;

    floatx4 acc[2][2];
    #pragma unroll
    for (int i = 0; i < 2; ++i)
        #pragma unroll
        for (int j = 0; j < 2; ++j)
            acc[i][j] = (floatx4){0.f, 0.f, 0.f, 0.f};

    for (int k0 = 0; k0 < K; k0 += TK) {
        int ar = row0 + a_r;
        uint4 av = (ar < M) ? *(const uint4*)(Ap + (size_t)ar * K + k0 + a_kc)
                            : make_uint4(0, 0, 0, 0);
        uint4 bv[2][2];
        #pragma unroll
        for (int p = 0; p < 2; ++p) {
            const uint4* pb = (const uint4*)(Btp + (size_t)(col0 + b_r + p * 64) * K + k0 + b_kc);
            bv[p][0] = pb[0];  bv[p][1] = pb[1];
        }
        __syncthreads();          // prev iter frag reads done
        {   // A unpack: 4 uints -> bfs4 hi/lo
            unsigned ua[4] = {av.x, av.y, av.z, av.w};
            bfs4 ah4, al4;
            #pragma unroll
            for (int j = 0; j < 4; ++j) {
                ah4[j] = (short)(ua[j] >> 16);  al4[j] = (short)(ua[j] & 0xFFFFu);
            }
            *(bfs4*)&As_hi[a_r * LDK + a_kc] = ah4;
            *(bfs4*)&As_lo[a_r * LDK + a_kc] = al4;
        }
        #pragma unroll
        for (int p = 0; p < 2; ++p) {
            int r = b_r + p * 64;
            unsigned ub[8] = {bv[p][0].x, bv[p][0].y, bv[p][0].z, bv[p][0].w,
                              bv[p][1].x, bv[p][1].y, bv[p][1].z, bv[p][1].w};
            short8 bhs, bls;
            #pragma unroll
            for (int j = 0; j < 8; ++j) {
                bhs[j] = (short)(ub[j] >> 16);  bls[j] = (short)(ub[j] & 0xFFFFu);
            }
            *(short8*)&Bs_hi[r * LDK + b_kc] = bhs;
            *(short8*)&Bs_lo[r * LDK + b_kc] = bls;
        }
        __syncthreads();
        short8 ah[2], al[2], bh[2], bl[2];
        int ka = (lane >> 4) * 8;
        #pragma unroll
        for (int mi = 0; mi < 2; ++mi) {
            int rr = mi * 16 + (lane & 15);
            ah[mi] = *(const short8*)&As_hi[rr * LDK + ka];
            al[mi] = *(const short8*)&As_lo[rr * LDK + ka];
        }
        #pragma unroll
        for (int ni = 0; ni < 2; ++ni) {
            int cc = n0w + ni * 16 + (lane & 15);
            bh[ni] = *(const short8*)&Bs_hi[cc * LDK + ka];
            bl[ni] = *(const short8*)&Bs_lo[cc * LDK + ka];
        }
        #pragma unroll
        for (int mi = 0; mi < 2; ++mi)
            #pragma unroll
            for (int ni = 0; ni < 2; ++ni) {
                acc[mi][ni] = __builtin_amdgcn_mfma_f32_16x16x32_bf16(al[mi], bh[ni], acc[mi][ni], 0, 0, 0);
                acc[mi][ni] = __builtin_amdgcn_mfma_f32_16x16x32_bf16(ah[mi], bl[ni], acc[mi][ni], 0, 0, 0);
                acc[mi][ni] = __builtin_amdgcn_mfma_f32_16x16x32_bf16(ah[mi], bh[ni], acc[mi][ni], 0, 0, 0);
            }
    }

    // epilogue: C/D mapping col=lane&15, row=(lane>>4)*4+reg
    #pragma unroll
    for (int mi = 0; mi < 2; ++mi) {
        #pragma unroll
        for (int reg = 0; reg < 4; ++reg) {
            int r = row0 + mi * 16 + (lane >> 4) * 4 + reg;
            if (r < M) {
                #pragma unroll
                for (int ni = 0; ni < 2; ++ni) {
                    int c = col0 + n0w + ni * 16 + (lane & 15);
                    float v = acc[mi][ni][reg];
                    if (bias) v += bias[c];
                    if (relu_flag) v = fmaxf(v, 0.0f);
                    if (Cf)      Cf[(size_t)r * N + c] = v;
                    else if (Cp) Cp[(size_t)r * N + c] = pack_hilo(v);
                    else         Cb[(size_t)r * N + c] = f2bf(v);
                }
            }
        }
    }
}

// ---------------------------------------------------------------------------
extern "C" void kernel_launch(void* const* d_in, const int* in_sizes, int n_in,
                              void* d_out, int out_size, void* d_ws, size_t ws_size,
                              hipStream_t stream) {
    const float* x  = (const float*)d_in[0];
    const int*   ei = (const int*)d_in[1];
    const float* W1 = (const float*)d_in[2];
    const float* b1 = (const float*)d_in[3];
    const float* W2 = (const float*)d_in[4];
    const float* b2 = (const float*)d_in[5];

    const int n = in_sizes[0] / C_IN;          // 50000
    const int E = in_sizes[1] / 2;             // 800000

    const int* src = ei;
    const int* dst = ei + E;

    // workspace layout (~81 MB)
    unsigned short* h2b = (unsigned short*)d_ws;         // n*128 bf16
    unsigned* z1p = (unsigned*)(h2b + (size_t)n * C_OUT);// n*256 packed
    unsigned short* xb = (unsigned short*)(z1p + (size_t)n * C_HID); // n*128 bf16
    unsigned* w1t = (unsigned*)(xb + (size_t)n * C_IN);  // 128*256
    unsigned* w2t = w1t + C_IN * C_HID;                  // 256*128
    float*    dinv = (float*)(w2t + C_HID * C_OUT);      // n
    int* counts  = (int*)(dinv + n);                     // n (preserved)
    int* cursor  = counts + n;                           // n (separate)
    int* offsets = cursor + n;                           // n+1
    unsigned* csr_pk = (unsigned*)(offsets + n + 1);     // E uint (+64 slack)
    int* block_sums = (int*)(csr_pk + E + 64);           // 64
    int* block_base = block_sums + 64;                   // 64

    unsigned* agg0p = (unsigned*)d_out;    // n*128 packed, overwritten by final out
    float*    outp  = (float*)d_out;

    const int nb = (n + SCHUNK - 1) / SCHUNK;            // 49
    const int count4 = n * C_IN / 4;                     // 1.6M
    const int nb_deg = (E + 255) / 256;                  // 3125
    const int nb_x   = (count4 + 255) / 256;             // 6250
    const int nb_w1  = (C_IN * C_HID + 255) / 256;       // 128
    const int nb_w2  = (C_HID * C_OUT + 255) / 256;      // 128

    // ---- fused pre-pass: deg histogram + x/W casts (independent work) ----
    hipMemsetAsync(counts, 0, (size_t)n * sizeof(int), stream);
    fused_pre<<<nb_deg + nb_x + nb_w1 + nb_w2, 256, 0, stream>>>(
        dst, counts, E, x, (unsigned*)xb, count4, W1, w1t, W2, w2t,
        nb_deg, nb_x, nb_w1);

    // ---- CSR build ----
    scan_reduce<<<nb, 256, 0, stream>>>(counts, block_sums, n);
    scan_sums<<<1, 64, 0, stream>>>(block_sums, block_base, nb, offsets, n, E);
    scan_apply<<<nb, 256, 0, stream>>>(counts, block_base, offsets, cursor, dinv, n);
    fill_csr_part<<<8 * 391, 256, 0, stream>>>(src, dst, counts, cursor, csr_pk, E, n);

    const int agg_blocks = (n + 3) / 4;

    // ---- layer 1: agg0 = Ahat*X (packed) ; z1 = relu(agg0@W1 + b1) (packed) ----
    agg_kernel<<<agg_blocks, 256, 0, stream>>>(xb, offsets, csr_pk,
                                               dinv, nullptr, nullptr, agg0p, 0, n);
    {
        dim3 grid((n + TM - 1) / TM, C_HID / TN);        // (1563, 2)
        mfma_gemm<<<grid, 256, 0, stream>>>(agg0p, w1t, b1, nullptr, z1p, nullptr,
                                            n, C_IN, C_HID, 1);
    }

    // ---- layer 2: h2 = z1@W2 (bf16) ; out = relu(Ahat*h2 + b2) ----
    {
        dim3 grid((n + TM - 1) / TM, C_OUT / TN);        // (1563, 1)
        mfma_gemm<<<grid, 256, 0, stream>>>(z1p, w2t, nullptr, nullptr, nullptr, h2b,
                                            n, C_HID, C_OUT, 0);
    }
    agg_kernel<<<agg_blocks, 256, 0, stream>>>(h2b, offsets, csr_pk,
                                               dinv, b2, outp, nullptr, 1, n);
}